// Round 5
// baseline (400.576 us; speedup 1.0000x reference)
//
#include <hip/hip_runtime.h>
#include <hip/hip_bf16.h>

// Pipeline (no global atomics anywhere — round-3/4 profiles showed both fp32
// and int global atomics write through to HBM per-op on MI355X):
//   k_hist        : privatized LDS histograms -> partial[a][c][n]
//   k_reduce_dinv : deg/indeg totals, dinv = rsqrt(deg)
//   k_scan1/2/3   : ptr = exscan(indeg)   (segment starts)
//   k_base        : base[c][n] = ptr[n] + prefix_c(partial_ind)
//   k_bin2        : counting-sort edges into csr_row (LDS atomics only)
//   dual_gemm / gather / dual_gemm / gather / out_gemm

#define NCHUNK 16   // edge chunks
#define NRANGE 4    // node ranges (range <= 12800 for N=50000)
#define HIST_MAX 12800

// ---------- partial histograms: a=0 deg over row, a=1 indeg over col ----------
__global__ __launch_bounds__(256) void k_hist(const int* __restrict__ ei,
                                              int* __restrict__ partial,
                                              int N, int E, int range) {
  __shared__ int hist[HIST_MAX];
  int c = blockIdx.x % NCHUNK;
  int r = (blockIdx.x / NCHUNK) % NRANGE;
  int a = blockIdx.x / (NCHUNK * NRANGE);
  const int* ids = ei + (size_t)a * E;
  int lo = r * range;
  int hi = min(N, lo + range);
  int len = hi - lo;
  for (int i = threadIdx.x; i < len; i += 256) hist[i] = 0;
  __syncthreads();
  int e0 = (int)((long long)E * c / NCHUNK);
  int e1 = (int)((long long)E * (c + 1) / NCHUNK);
  for (int e = e0 + threadIdx.x; e < e1; e += 256) {
    int id = ids[e];
    if (id >= lo && id < hi) atomicAdd(&hist[id - lo], 1);  // LDS atomic
  }
  __syncthreads();
  int* dst = partial + ((size_t)a * NCHUNK + c) * N + lo;
  for (int i = threadIdx.x; i < len; i += 256) dst[i] = hist[i];
}

// ---------- reduce partials -> dinv, indeg ----------
__global__ __launch_bounds__(256) void k_reduce_dinv(const int* __restrict__ partial,
                                                     float* __restrict__ dinv,
                                                     int* __restrict__ indeg, int N) {
  int n = blockIdx.x * 256 + threadIdx.x;
  if (n >= N) return;
  int deg = 0, ind = 0;
#pragma unroll
  for (int c = 0; c < NCHUNK; ++c) {
    deg += partial[(size_t)c * N + n];
    ind += partial[((size_t)NCHUNK + c) * N + n];
  }
  dinv[n] = (deg > 0) ? (1.0f / sqrtf((float)deg)) : 0.0f;
  indeg[n] = ind;
}

// ---------- exclusive scan of indeg -> ptr ----------
__global__ __launch_bounds__(1024) void k_scan1(const int* __restrict__ in,
                                                int* __restrict__ out,
                                                int* __restrict__ bsum, int n) {
  __shared__ int s[1024];
  int g = blockIdx.x * 1024 + threadIdx.x;
  int v = (g < n) ? in[g] : 0;
  s[threadIdx.x] = v;
  __syncthreads();
  for (int off = 1; off < 1024; off <<= 1) {
    int tv = (threadIdx.x >= off) ? s[threadIdx.x - off] : 0;
    __syncthreads();
    s[threadIdx.x] += tv;
    __syncthreads();
  }
  if (g < n) out[g] = s[threadIdx.x] - v;
  if (threadIdx.x == 1023) bsum[blockIdx.x] = s[1023];
}

__global__ void k_scan2(int* __restrict__ bsum, int nb) {
  if (threadIdx.x == 0 && blockIdx.x == 0) {
    int acc = 0;
    for (int i = 0; i < nb; ++i) { int v = bsum[i]; bsum[i] = acc; acc += v; }
  }
}

__global__ __launch_bounds__(1024) void k_scan3(int* __restrict__ out,
                                                const int* __restrict__ bsum, int n) {
  int g = blockIdx.x * 1024 + threadIdx.x;
  if (g < n) out[g] += bsum[blockIdx.x];
}

// ---------- per-chunk placement bases ----------
__global__ __launch_bounds__(256) void k_base(const int* __restrict__ partial,
                                              const int* __restrict__ ptr,
                                              int* __restrict__ base, int N) {
  int n = blockIdx.x * 256 + threadIdx.x;
  if (n >= N) return;
  int run = ptr[n];
#pragma unroll
  for (int c = 0; c < NCHUNK; ++c) {
    base[(size_t)c * N + n] = run;
    run += partial[((size_t)NCHUNK + c) * N + n];
  }
}

// ---------- counting-sort binning (LDS atomics only) ----------
__global__ __launch_bounds__(256) void k_bin2(const int* __restrict__ ei,
                                              const int* __restrict__ base,
                                              int* __restrict__ csr_row,
                                              int N, int E, int range) {
  __shared__ int cnt[HIST_MAX];
  int c = blockIdx.x % NCHUNK;
  int r = blockIdx.x / NCHUNK;
  const int* row = ei;
  const int* col = ei + E;
  int lo = r * range;
  int hi = min(N, lo + range);
  int len = hi - lo;
  for (int i = threadIdx.x; i < len; i += 256) cnt[i] = 0;
  __syncthreads();
  int e0 = (int)((long long)E * c / NCHUNK);
  int e1 = (int)((long long)E * (c + 1) / NCHUNK);
  for (int e = e0 + threadIdx.x; e < e1; e += 256) {
    int cl = col[e];
    if (cl >= lo && cl < hi) {
      int off = atomicAdd(&cnt[cl - lo], 1);  // LDS atomic
      csr_row[base[(size_t)c * N + cl] + off] = row[e];  // plain store (L2-absorbed)
    }
  }
}

// ---------- dual GEMM: t = h@Wn (bf16 out), agg = h@Wi + bias ----------
// h and agg may ALIAS (in-place layer 2): each block touches only rows
// [64b,64b+64), stages each 16-row group into LDS before overwriting it.
template <bool RELU>
__global__ __launch_bounds__(256) void k_dual_gemm(
    const float* h,
    const float* __restrict__ Wn,
    const float* __restrict__ Wi,
    const float* __restrict__ bias,
    __hip_bfloat16* __restrict__ t, float* agg, int N) {
  __shared__ float Wn_s[64 * 64];
  __shared__ float Wi_s[64 * 64];
  __shared__ float b_s[64];
  __shared__ float h_s[16 * 64];

  const int tid = threadIdx.x;
  for (int i = tid; i < 4096; i += 256) {
    Wn_s[i] = Wn[i];
    Wi_s[i] = Wi[i];
  }
  if (tid < 64) b_s[tid] = bias[tid];

  const int j = tid & 63;
  const int quad = tid >> 6;
  const int r0 = blockIdx.x * 64;

  for (int g = 0; g < 4; ++g) {
    __syncthreads();
#pragma unroll
    for (int i = 0; i < 4; ++i) {
      int idx = tid + i * 256;
      int rr = idx >> 6;
      int cc = idx & 63;
      int rload = r0 + g * 16 + rr;
      float v = 0.0f;
      if (rload < N) {
        float xv = h[(size_t)rload * 64 + cc];
        v = RELU ? fmaxf(xv, 0.0f) : xv;
      }
      h_s[idx] = v;
    }
    __syncthreads();

    float acc_t[4] = {0.f, 0.f, 0.f, 0.f};
    float acc_a[4] = {0.f, 0.f, 0.f, 0.f};
#pragma unroll 8
    for (int k = 0; k < 64; ++k) {
      float wn = Wn_s[k * 64 + j];
      float wi = Wi_s[k * 64 + j];
#pragma unroll
      for (int rr = 0; rr < 4; ++rr) {
        float hk = h_s[(quad * 4 + rr) * 64 + k];
        acc_t[rr] = fmaf(hk, wn, acc_t[rr]);
        acc_a[rr] = fmaf(hk, wi, acc_a[rr]);
      }
    }
#pragma unroll
    for (int rr = 0; rr < 4; ++rr) {
      int r = r0 + g * 16 + quad * 4 + rr;
      if (r < N) {
        t[(size_t)r * 64 + j] = __float2bfloat16(acc_t[rr]);
        agg[(size_t)r * 64 + j] = acc_a[rr] + b_s[j];
      }
    }
  }
}

// ---------- CSR gather: agg[n] += sum_e t[row_e] * dinv[row_e]*dinv[n] ----------
__global__ __launch_bounds__(256) void k_gather(
    const int* __restrict__ csr_row, const int* __restrict__ ptr,
    const int* __restrict__ indeg, const float* __restrict__ dinv,
    const __hip_bfloat16* __restrict__ t, float* __restrict__ agg, int N) {
  int n = blockIdx.x * 4 + (threadIdx.x >> 6);
  if (n >= N) return;
  int lane = threadIdx.x & 63;
  int i = ptr[n];                 // segment start
  int end = i + indeg[n];
  float dn = dinv[n];
  float acc = agg[(size_t)n * 64 + lane];

  for (; i + 4 <= end; i += 4) {
    int r0 = csr_row[i], r1 = csr_row[i + 1], r2 = csr_row[i + 2], r3 = csr_row[i + 3];
    float v0 = __bfloat162float(t[(size_t)r0 * 64 + lane]);
    float v1 = __bfloat162float(t[(size_t)r1 * 64 + lane]);
    float v2 = __bfloat162float(t[(size_t)r2 * 64 + lane]);
    float v3 = __bfloat162float(t[(size_t)r3 * 64 + lane]);
    float n0 = dinv[r0] * dn, n1 = dinv[r1] * dn, n2 = dinv[r2] * dn, n3 = dinv[r3] * dn;
    acc = fmaf(v0, n0, acc);
    acc = fmaf(v1, n1, acc);
    acc = fmaf(v2, n2, acc);
    acc = fmaf(v3, n3, acc);
  }
  for (; i < end; ++i) {
    int r = csr_row[i];
    acc = fmaf(__bfloat162float(t[(size_t)r * 64 + lane]), dinv[r] * dn, acc);
  }
  agg[(size_t)n * 64 + lane] = acc;
}

// ---------- output GEMM: out = relu(h) @ Wo + bo ----------
__global__ __launch_bounds__(256) void k_out_gemm(
    const float* __restrict__ h,
    const float* __restrict__ Wo,   // [64,32]
    const float* __restrict__ bo,   // [32]
    float* __restrict__ out, int N) {
  __shared__ float Wo_s[64 * 32];
  __shared__ float bo_s[32];
  __shared__ float h_s[16 * 64];

  const int tid = threadIdx.x;
  for (int i = tid; i < 2048; i += 256) Wo_s[i] = Wo[i];
  if (tid < 32) bo_s[tid] = bo[tid];

  const int j = tid & 31;
  const int rsub = tid >> 5;
  const int r0 = blockIdx.x * 64;

  for (int g = 0; g < 4; ++g) {
    __syncthreads();
#pragma unroll
    for (int i = 0; i < 4; ++i) {
      int idx = tid + i * 256;
      int rr = idx >> 6;
      int cc = idx & 63;
      int rload = r0 + g * 16 + rr;
      float v = 0.0f;
      if (rload < N) v = fmaxf(h[(size_t)rload * 64 + cc], 0.0f);
      h_s[idx] = v;
    }
    __syncthreads();
#pragma unroll
    for (int rh = 0; rh < 2; ++rh) {
      int rloc = rsub + rh * 8;
      float acc = 0.0f;
#pragma unroll 8
      for (int k = 0; k < 64; ++k)
        acc = fmaf(h_s[rloc * 64 + k], Wo_s[k * 32 + j], acc);
      int r = r0 + g * 16 + rloc;
      if (r < N) out[(size_t)r * 32 + j] = acc + bo_s[j];
    }
  }
}

extern "C" void kernel_launch(void* const* d_in, const int* in_sizes, int n_in,
                              void* d_out, int out_size, void* d_ws, size_t ws_size,
                              hipStream_t stream) {
  const float* x = (const float*)d_in[0];
  const int* ei = (const int*)d_in[1];
  const float* W_in1 = (const float*)d_in[2];
  const float* W_neigh1 = (const float*)d_in[3];
  const float* bias1 = (const float*)d_in[4];
  const float* W_in2 = (const float*)d_in[5];
  const float* W_neigh2 = (const float*)d_in[6];
  const float* bias2 = (const float*)d_in[7];
  const float* W_out = (const float*)d_in[8];
  const float* b_out = (const float*)d_in[9];
  float* out = (float*)d_out;

  const int N = in_sizes[0] / 64;
  const int E = in_sizes[1] / 2;

  // workspace: dinv, indeg, ptr, bsum, csr_row, partial(2*C*N), base(C*N),
  // t(bf16), agg(fp32).  ~32.6 MB total.
  char* ws = (char*)d_ws;
  size_t off = 0;
  auto alloc = [&](size_t bytes) -> void* {
    void* p = ws + off;
    off += (bytes + 255) & ~(size_t)255;
    return p;
  };
  float* dinv = (float*)alloc((size_t)N * 4);
  int* indeg = (int*)alloc((size_t)N * 4);
  int* ptr = (int*)alloc((size_t)N * 4);
  int* bsum = (int*)alloc(256);
  int* csr_row = (int*)alloc((size_t)E * 4);
  int* partial = (int*)alloc((size_t)2 * NCHUNK * N * 4);
  int* base = (int*)alloc((size_t)NCHUNK * N * 4);
  __hip_bfloat16* t = (__hip_bfloat16*)alloc((size_t)N * 64 * 2);
  float* agg = (float*)alloc((size_t)N * 64 * 4);
  (void)ws_size;

  int range = (N + NRANGE - 1) / NRANGE;  // 12500 <= HIST_MAX
  int gN = (N + 255) / 256;
  int gRows = (N + 63) / 64;
  int gNode = (N + 3) / 4;
  int nb = (N + 1023) / 1024;

  k_hist<<<2 * NRANGE * NCHUNK, 256, 0, stream>>>(ei, partial, N, E, range);
  k_reduce_dinv<<<gN, 256, 0, stream>>>(partial, dinv, indeg, N);
  k_scan1<<<nb, 1024, 0, stream>>>(indeg, ptr, bsum, N);
  k_scan2<<<1, 64, 0, stream>>>(bsum, nb);
  k_scan3<<<nb, 1024, 0, stream>>>(ptr, bsum, N);
  k_base<<<gN, 256, 0, stream>>>(partial, ptr, base, N);
  k_bin2<<<NRANGE * NCHUNK, 256, 0, stream>>>(ei, base, csr_row, N, E, range);

  // layer 1
  k_dual_gemm<false><<<gRows, 256, 0, stream>>>(x, W_neigh1, W_in1, bias1, t, agg, N);
  k_gather<<<gNode, 256, 0, stream>>>(csr_row, ptr, indeg, dinv, t, agg, N);

  // layer 2 (in-place on agg)
  k_dual_gemm<true><<<gRows, 256, 0, stream>>>(agg, W_neigh2, W_in2, bias2, t, agg, N);
  k_gather<<<gNode, 256, 0, stream>>>(csr_row, ptr, indeg, dinv, t, agg, N);

  // output
  k_out_gemm<<<gRows, 256, 0, stream>>>(agg, W_out, b_out, out, N);
}

// Round 6
// 285.331 us; speedup vs baseline: 1.4039x; 1.4039x over previous
//
#include <hip/hip_runtime.h>
#include <hip/hip_bf16.h>

// Pipeline (no global atomics — rounds 3/4 showed global atomics write through
// to HBM per-op). Round 5 lesson: the build kernels MUST launch enough blocks;
// 64 blocks = 2.6% occupancy = 111 us. Now NRANGE=16 (12.5 KB LDS), 1024-thread
// blocks: k_hist 512 blocks, k_bin2 256 blocks x 16 waves.
//   k_hist        : privatized LDS histograms -> partial[a][c][n]
//   k_reduce_dinv : deg/indeg totals, dinv = rsqrt(deg)
//   k_scan1/2/3   : ptr = exscan(indeg)   (segment starts)
//   k_base        : base[c][n] = ptr[n] + prefix_c(partial_ind)
//   k_bin2        : counting-sort edges into csr_row (LDS atomics only)
//   dual_gemm / gather / dual_gemm / gather / out_gemm

#define NCHUNK 16   // edge chunks
#define NRANGE 16   // node ranges (range = 3125 for N=50000)
#define HIST_MAX 3200

// ---------- partial histograms: a=0 deg over row, a=1 indeg over col ----------
__global__ __launch_bounds__(1024) void k_hist(const int* __restrict__ ei,
                                               int* __restrict__ partial,
                                               int N, int E, int range) {
  __shared__ int hist[HIST_MAX];
  int c = blockIdx.x % NCHUNK;
  int r = (blockIdx.x / NCHUNK) % NRANGE;
  int a = blockIdx.x / (NCHUNK * NRANGE);
  const int* ids = ei + (size_t)a * E;
  int lo = r * range;
  int hi = min(N, lo + range);
  int len = hi - lo;
  for (int i = threadIdx.x; i < len; i += 1024) hist[i] = 0;
  __syncthreads();
  int e0 = (int)((long long)E * c / NCHUNK);
  int e1 = (int)((long long)E * (c + 1) / NCHUNK);
  for (int e = e0 + threadIdx.x; e < e1; e += 1024) {
    int id = ids[e];
    if (id >= lo && id < hi) atomicAdd(&hist[id - lo], 1);  // LDS atomic
  }
  __syncthreads();
  int* dst = partial + ((size_t)a * NCHUNK + c) * N + lo;
  for (int i = threadIdx.x; i < len; i += 1024) dst[i] = hist[i];
}

// ---------- reduce partials -> dinv, indeg ----------
__global__ __launch_bounds__(256) void k_reduce_dinv(const int* __restrict__ partial,
                                                     float* __restrict__ dinv,
                                                     int* __restrict__ indeg, int N) {
  int n = blockIdx.x * 256 + threadIdx.x;
  if (n >= N) return;
  int deg = 0, ind = 0;
#pragma unroll
  for (int c = 0; c < NCHUNK; ++c) {
    deg += partial[(size_t)c * N + n];
    ind += partial[((size_t)NCHUNK + c) * N + n];
  }
  dinv[n] = (deg > 0) ? (1.0f / sqrtf((float)deg)) : 0.0f;
  indeg[n] = ind;
}

// ---------- exclusive scan of indeg -> ptr ----------
__global__ __launch_bounds__(1024) void k_scan1(const int* __restrict__ in,
                                                int* __restrict__ out,
                                                int* __restrict__ bsum, int n) {
  __shared__ int s[1024];
  int g = blockIdx.x * 1024 + threadIdx.x;
  int v = (g < n) ? in[g] : 0;
  s[threadIdx.x] = v;
  __syncthreads();
  for (int off = 1; off < 1024; off <<= 1) {
    int tv = (threadIdx.x >= off) ? s[threadIdx.x - off] : 0;
    __syncthreads();
    s[threadIdx.x] += tv;
    __syncthreads();
  }
  if (g < n) out[g] = s[threadIdx.x] - v;
  if (threadIdx.x == 1023) bsum[blockIdx.x] = s[1023];
}

__global__ void k_scan2(int* __restrict__ bsum, int nb) {
  if (threadIdx.x == 0 && blockIdx.x == 0) {
    int acc = 0;
    for (int i = 0; i < nb; ++i) { int v = bsum[i]; bsum[i] = acc; acc += v; }
  }
}

__global__ __launch_bounds__(1024) void k_scan3(int* __restrict__ out,
                                                const int* __restrict__ bsum, int n) {
  int g = blockIdx.x * 1024 + threadIdx.x;
  if (g < n) out[g] += bsum[blockIdx.x];
}

// ---------- per-chunk placement bases ----------
__global__ __launch_bounds__(256) void k_base(const int* __restrict__ partial,
                                              const int* __restrict__ ptr,
                                              int* __restrict__ base, int N) {
  int n = blockIdx.x * 256 + threadIdx.x;
  if (n >= N) return;
  int run = ptr[n];
#pragma unroll
  for (int c = 0; c < NCHUNK; ++c) {
    base[(size_t)c * N + n] = run;
    run += partial[((size_t)NCHUNK + c) * N + n];
  }
}

// ---------- counting-sort binning (LDS atomics; base slice preloaded to LDS) ----------
__global__ __launch_bounds__(1024) void k_bin2(const int* __restrict__ ei,
                                               const int* __restrict__ base,
                                               int* __restrict__ csr_row,
                                               int N, int E, int range) {
  __shared__ int cnt[HIST_MAX];
  __shared__ int base_s[HIST_MAX];
  int c = blockIdx.x % NCHUNK;
  int r = blockIdx.x / NCHUNK;
  const int* row = ei;
  const int* col = ei + E;
  int lo = r * range;
  int hi = min(N, lo + range);
  int len = hi - lo;
  const int* bsrc = base + (size_t)c * N + lo;
  for (int i = threadIdx.x; i < len; i += 1024) {
    cnt[i] = 0;
    base_s[i] = bsrc[i];
  }
  __syncthreads();
  int e0 = (int)((long long)E * c / NCHUNK);
  int e1 = (int)((long long)E * (c + 1) / NCHUNK);
  for (int e = e0 + threadIdx.x; e < e1; e += 1024) {
    int cl = col[e];
    int rw = row[e];  // unconditional coalesced load
    if (cl >= lo && cl < hi) {
      int off = atomicAdd(&cnt[cl - lo], 1);          // LDS atomic
      csr_row[base_s[cl - lo] + off] = rw;            // plain store (L2-absorbed)
    }
  }
}

// ---------- dual GEMM: t = h@Wn (bf16 out), agg = h@Wi + bias ----------
// h and agg may ALIAS (in-place layer 2): each block touches only rows
// [64b,64b+64), stages each 16-row group into LDS before overwriting it.
template <bool RELU>
__global__ __launch_bounds__(256) void k_dual_gemm(
    const float* h,
    const float* __restrict__ Wn,
    const float* __restrict__ Wi,
    const float* __restrict__ bias,
    __hip_bfloat16* __restrict__ t, float* agg, int N) {
  __shared__ float Wn_s[64 * 64];
  __shared__ float Wi_s[64 * 64];
  __shared__ float b_s[64];
  __shared__ float h_s[16 * 64];

  const int tid = threadIdx.x;
  for (int i = tid; i < 4096; i += 256) {
    Wn_s[i] = Wn[i];
    Wi_s[i] = Wi[i];
  }
  if (tid < 64) b_s[tid] = bias[tid];

  const int j = tid & 63;
  const int quad = tid >> 6;
  const int r0 = blockIdx.x * 64;

  for (int g = 0; g < 4; ++g) {
    __syncthreads();
#pragma unroll
    for (int i = 0; i < 4; ++i) {
      int idx = tid + i * 256;
      int rr = idx >> 6;
      int cc = idx & 63;
      int rload = r0 + g * 16 + rr;
      float v = 0.0f;
      if (rload < N) {
        float xv = h[(size_t)rload * 64 + cc];
        v = RELU ? fmaxf(xv, 0.0f) : xv;
      }
      h_s[idx] = v;
    }
    __syncthreads();

    float acc_t[4] = {0.f, 0.f, 0.f, 0.f};
    float acc_a[4] = {0.f, 0.f, 0.f, 0.f};
#pragma unroll 8
    for (int k = 0; k < 64; ++k) {
      float wn = Wn_s[k * 64 + j];
      float wi = Wi_s[k * 64 + j];
#pragma unroll
      for (int rr = 0; rr < 4; ++rr) {
        float hk = h_s[(quad * 4 + rr) * 64 + k];
        acc_t[rr] = fmaf(hk, wn, acc_t[rr]);
        acc_a[rr] = fmaf(hk, wi, acc_a[rr]);
      }
    }
#pragma unroll
    for (int rr = 0; rr < 4; ++rr) {
      int r = r0 + g * 16 + quad * 4 + rr;
      if (r < N) {
        t[(size_t)r * 64 + j] = __float2bfloat16(acc_t[rr]);
        agg[(size_t)r * 64 + j] = acc_a[rr] + b_s[j];
      }
    }
  }
}

// ---------- CSR gather: agg[n] += sum_e t[row_e] * dinv[row_e]*dinv[n] ----------
__global__ __launch_bounds__(256) void k_gather(
    const int* __restrict__ csr_row, const int* __restrict__ ptr,
    const int* __restrict__ indeg, const float* __restrict__ dinv,
    const __hip_bfloat16* __restrict__ t, float* __restrict__ agg, int N) {
  int n = blockIdx.x * 4 + (threadIdx.x >> 6);
  if (n >= N) return;
  int lane = threadIdx.x & 63;
  int i = ptr[n];                 // segment start
  int end = i + indeg[n];
  float dn = dinv[n];
  float acc = agg[(size_t)n * 64 + lane];

  for (; i + 4 <= end; i += 4) {
    int r0 = csr_row[i], r1 = csr_row[i + 1], r2 = csr_row[i + 2], r3 = csr_row[i + 3];
    float v0 = __bfloat162float(t[(size_t)r0 * 64 + lane]);
    float v1 = __bfloat162float(t[(size_t)r1 * 64 + lane]);
    float v2 = __bfloat162float(t[(size_t)r2 * 64 + lane]);
    float v3 = __bfloat162float(t[(size_t)r3 * 64 + lane]);
    float n0 = dinv[r0] * dn, n1 = dinv[r1] * dn, n2 = dinv[r2] * dn, n3 = dinv[r3] * dn;
    acc = fmaf(v0, n0, acc);
    acc = fmaf(v1, n1, acc);
    acc = fmaf(v2, n2, acc);
    acc = fmaf(v3, n3, acc);
  }
  for (; i < end; ++i) {
    int r = csr_row[i];
    acc = fmaf(__bfloat162float(t[(size_t)r * 64 + lane]), dinv[r] * dn, acc);
  }
  agg[(size_t)n * 64 + lane] = acc;
}

// ---------- output GEMM: out = relu(h) @ Wo + bo ----------
__global__ __launch_bounds__(256) void k_out_gemm(
    const float* __restrict__ h,
    const float* __restrict__ Wo,   // [64,32]
    const float* __restrict__ bo,   // [32]
    float* __restrict__ out, int N) {
  __shared__ float Wo_s[64 * 32];
  __shared__ float bo_s[32];
  __shared__ float h_s[16 * 64];

  const int tid = threadIdx.x;
  for (int i = tid; i < 2048; i += 256) Wo_s[i] = Wo[i];
  if (tid < 32) bo_s[tid] = bo[tid];

  const int j = tid & 31;
  const int rsub = tid >> 5;
  const int r0 = blockIdx.x * 64;

  for (int g = 0; g < 4; ++g) {
    __syncthreads();
#pragma unroll
    for (int i = 0; i < 4; ++i) {
      int idx = tid + i * 256;
      int rr = idx >> 6;
      int cc = idx & 63;
      int rload = r0 + g * 16 + rr;
      float v = 0.0f;
      if (rload < N) v = fmaxf(h[(size_t)rload * 64 + cc], 0.0f);
      h_s[idx] = v;
    }
    __syncthreads();
#pragma unroll
    for (int rh = 0; rh < 2; ++rh) {
      int rloc = rsub + rh * 8;
      float acc = 0.0f;
#pragma unroll 8
      for (int k = 0; k < 64; ++k)
        acc = fmaf(h_s[rloc * 64 + k], Wo_s[k * 32 + j], acc);
      int r = r0 + g * 16 + rloc;
      if (r < N) out[(size_t)r * 32 + j] = acc + bo_s[j];
    }
  }
}

extern "C" void kernel_launch(void* const* d_in, const int* in_sizes, int n_in,
                              void* d_out, int out_size, void* d_ws, size_t ws_size,
                              hipStream_t stream) {
  const float* x = (const float*)d_in[0];
  const int* ei = (const int*)d_in[1];
  const float* W_in1 = (const float*)d_in[2];
  const float* W_neigh1 = (const float*)d_in[3];
  const float* bias1 = (const float*)d_in[4];
  const float* W_in2 = (const float*)d_in[5];
  const float* W_neigh2 = (const float*)d_in[6];
  const float* bias2 = (const float*)d_in[7];
  const float* W_out = (const float*)d_in[8];
  const float* b_out = (const float*)d_in[9];
  float* out = (float*)d_out;

  const int N = in_sizes[0] / 64;
  const int E = in_sizes[1] / 2;

  // workspace: dinv, indeg, ptr, bsum, csr_row, partial(2*C*N), base(C*N),
  // t(bf16), agg(fp32).  ~32.6 MB total (same as round 5, known-good).
  char* ws = (char*)d_ws;
  size_t off = 0;
  auto alloc = [&](size_t bytes) -> void* {
    void* p = ws + off;
    off += (bytes + 255) & ~(size_t)255;
    return p;
  };
  float* dinv = (float*)alloc((size_t)N * 4);
  int* indeg = (int*)alloc((size_t)N * 4);
  int* ptr = (int*)alloc((size_t)N * 4);
  int* bsum = (int*)alloc(256);
  int* csr_row = (int*)alloc((size_t)E * 4);
  int* partial = (int*)alloc((size_t)2 * NCHUNK * N * 4);
  int* base = (int*)alloc((size_t)NCHUNK * N * 4);
  __hip_bfloat16* t = (__hip_bfloat16*)alloc((size_t)N * 64 * 2);
  float* agg = (float*)alloc((size_t)N * 64 * 4);
  (void)ws_size;

  int range = (N + NRANGE - 1) / NRANGE;  // 3125 <= HIST_MAX
  int gN = (N + 255) / 256;
  int gRows = (N + 63) / 64;
  int gNode = (N + 3) / 4;
  int nb = (N + 1023) / 1024;

  k_hist<<<2 * NRANGE * NCHUNK, 1024, 0, stream>>>(ei, partial, N, E, range);
  k_reduce_dinv<<<gN, 256, 0, stream>>>(partial, dinv, indeg, N);
  k_scan1<<<nb, 1024, 0, stream>>>(indeg, ptr, bsum, N);
  k_scan2<<<1, 64, 0, stream>>>(bsum, nb);
  k_scan3<<<nb, 1024, 0, stream>>>(ptr, bsum, N);
  k_base<<<gN, 256, 0, stream>>>(partial, ptr, base, N);
  k_bin2<<<NRANGE * NCHUNK, 1024, 0, stream>>>(ei, base, csr_row, N, E, range);

  // layer 1
  k_dual_gemm<false><<<gRows, 256, 0, stream>>>(x, W_neigh1, W_in1, bias1, t, agg, N);
  k_gather<<<gNode, 256, 0, stream>>>(csr_row, ptr, indeg, dinv, t, agg, N);

  // layer 2 (in-place on agg)
  k_dual_gemm<true><<<gRows, 256, 0, stream>>>(agg, W_neigh2, W_in2, bias2, t, agg, N);
  k_gather<<<gNode, 256, 0, stream>>>(csr_row, ptr, indeg, dinv, t, agg, N);

  // output
  k_out_gemm<<<gRows, 256, 0, stream>>>(agg, W_out, b_out, out, N);
}